// Round 4
// baseline (532.141 us; speedup 1.0000x reference)
//
#include <hip/hip_runtime.h>
#include <hip/hip_bf16.h>

typedef __attribute__((ext_vector_type(8))) short short8;
typedef __attribute__((ext_vector_type(4))) short short4v;
typedef __attribute__((ext_vector_type(4))) float floatx4;

#define N_CELLS  500000
#define B_SAMP   512
#define D_X      128
#define D_Z      32
#define H_DIM    256
#define D_OUT    16

#define M_TILE   128
#define NBLK     3907          // ceil(500000/128); last block has 32 valid cells
#define LDH      264           // sH row stride (bf16): 528B
#define SP_LD    20            // GEMM3 partial row stride (f32): 80B

#define NREP     64

// workspace layout (bytes), 16B aligned
#define OFF_W1P   0            // 16*4*512*2   = 65536
#define OFF_W2P   65536        // 16*8*512*2   = 131072
#define OFF_W3P   196608       // 1*8*512*2    = 8192
#define OFF_ZW    204800       // 512*256*4    = 524288
#define OFF_ACC   729088       // 64*8192*4    = 2097152
#define OFF_CNT   2826240      // 64*512*4     = 131072
#define OFF_C2S   2957312      // 500000*4     = 2000000

#define W1_BLKS   128
#define W2_BLKS   256
#define W3_BLKS   16
#define ZW_BLKS   512
#define C2S_BLKS  1954

__device__ __forceinline__ short bfb(float x) {
    union { __hip_bfloat16 h; short s; } u;
    u.h = __float2bfloat16(x);
    return u.s;
}
__device__ __forceinline__ int pack2(float a, float b) {
    return ((int)(unsigned short)bfb(a)) | ((int)bfb(b) << 16);
}

// prep: pack W1(K=128, ln2-folded)/W2/W3 into MFMA fragment order;
// ZW1[b][n] = Z[b,:]@W1[128:160,n] + b1[n]; c2s[cell]=sidx[c2b[cell]];
// counts histogram (MLP-independent) into replicated cnts.
// accs/cnts zeroed by hipMemsetAsync before this launch.
__global__ __launch_bounds__(256)
void prep(const float* __restrict__ W1, const float* __restrict__ b1,
          const float* __restrict__ W2, const float* __restrict__ W3,
          const float* __restrict__ Z,
          const int* __restrict__ c2b, const int* __restrict__ sidx,
          __hip_bfloat16* __restrict__ w1p, __hip_bfloat16* __restrict__ w2p,
          __hip_bfloat16* __restrict__ w3p, float* __restrict__ zw1,
          float* __restrict__ cnts, int* __restrict__ c2s) {
    int bid = blockIdx.x;
    int tid = threadIdx.x;
    if (bid < W1_BLKS + W2_BLKS + W3_BLKS) {
        const float* W; __hip_bfloat16* dst; int N, kS, idx; float scale;
        if (bid < W1_BLKS) {
            idx = bid * 256 + tid; W = W1; dst = w1p; N = H_DIM; kS = 4;
            scale = 0.6931471805599453f;          // ln2: staging uses log2
        } else if (bid < W1_BLKS + W2_BLKS) {
            idx = (bid - W1_BLKS) * 256 + tid; W = W2; dst = w2p; N = H_DIM; kS = 8;
            scale = 1.0f;
        } else {
            idx = (bid - W1_BLKS - W2_BLKS) * 256 + tid; W = W3; dst = w3p; N = D_OUT; kS = 8;
            scale = 1.0f;
        }
        int j = idx & 7;
        int L = (idx >> 3) & 63;
        int s = (idx >> 9) % kS;
        int t = idx / (kS << 9);
        int k = s * 32 + ((L >> 4) << 3) + j;
        int n = t * 16 + (L & 15);
        dst[idx] = __float2bfloat16(W[(size_t)k * N + n] * scale);
        return;
    }
    bid -= W1_BLKS + W2_BLKS + W3_BLKS;
    if (bid < ZW_BLKS) {
        int s = bid;
        float a = b1[tid];
        const float* zr = Z + (size_t)s * D_Z;
        const float* wr = W1 + (size_t)D_X * H_DIM + tid;
#pragma unroll 8
        for (int k = 0; k < D_Z; ++k) a += zr[k] * wr[(size_t)k * H_DIM];
        zw1[(size_t)s * H_DIM + tid] = a;
        return;
    }
    bid -= ZW_BLKS;
    int i = bid * 256 + tid;
    if (i < N_CELLS) {
        int si = sidx[c2b[i]];
        c2s[i] = si;
        atomicAdd(&cnts[(size_t)(bid & (NREP - 1)) * B_SAMP + si], 1.0f);
    }
}

// 128 cells/block, 512 threads (8 waves: 2 cell-halves x 4 N-quarters; each
// wave owns 4 M-fragments). Single LDS buffer: Xp staged in cols 0..127,
// GEMM1 overwrites in-place with H0; H1 stays in registers — GEMM3 operands
// built by in-wave __shfl fragment redistribution; GEMM3 partials alias the
// dead sH. 5 barriers per 128 cells, LDS 68KB -> 2 blocks/CU.
__global__ __launch_bounds__(512, 4)
void fused_mlp(const float* __restrict__ X, const int* __restrict__ c2b,
               const int* __restrict__ c2s, const float* __restrict__ b2,
               const float* __restrict__ b3,
               const __hip_bfloat16* __restrict__ w1p,
               const __hip_bfloat16* __restrict__ w2p,
               const __hip_bfloat16* __restrict__ w3p,
               const float* __restrict__ zw1,
               float* __restrict__ accs, float* __restrict__ cnts) {
    __shared__ __align__(16) short sH[M_TILE][LDH];    // Xp -> H0 -> sP alias
    __shared__ int sSI[M_TILE];
    float (*sP)[M_TILE][SP_LD] = (float (*)[M_TILE][SP_LD])sH;  // 4*128*20*4=40KB

    const int tid = threadIdx.x;
    const int w   = tid >> 6;     // wave 0..7
    const int L   = tid & 63;
    const int q   = L >> 4;
    const int ln  = L & 15;
    const int wm  = w >> 2;       // cell 64-half
    const int wn  = w & 3;        // N-quarter
    const int base = blockIdx.x * M_TILE;

    // ---- GEMM1 C-init: gather ZW1 rows (issued early, hides under staging) ----
    floatx4 acc[4][4];
#pragma unroll
    for (int mt = 0; mt < 4; ++mt) {
        int g = base + wm * 64 + mt * 16 + ln;
        if (g >= N_CELLS) g = N_CELLS - 1;
        int cbm = c2b[g];
#pragma unroll
        for (int nt = 0; nt < 4; ++nt)
            acc[mt][nt] = *(const floatx4*)(zw1 + (size_t)cbm * H_DIM + wn * 64 + nt * 16 + q * 4);
    }

    // ---- stage Xp = log2(1+X) bf16 into sH cols 0..127 ----
#pragma unroll
    for (int i = 0; i < 8; ++i) {
        int idx = tid + i * 512;          // 128 rows * 32 float4
        int row = idx >> 5, c4 = idx & 31;
        int gr = base + row; if (gr >= N_CELLS) gr = N_CELLS - 1;
        float4 v = *(const float4*)(X + (size_t)gr * D_X + c4 * 4);
        short4v pk;
        pk.x = bfb(__log2f(1.0f + v.x));
        pk.y = bfb(__log2f(1.0f + v.y));
        pk.z = bfb(__log2f(1.0f + v.z));
        pk.w = bfb(__log2f(1.0f + v.w));
        *(short4v*)&sH[row][c4 * 4] = pk;
    }
    if (tid < M_TILE) {
        int gr = base + tid; if (gr >= N_CELLS) gr = N_CELLS - 1;
        sSI[tid] = c2s[gr];
    }
    __syncthreads();                                            // b1: Xp ready

    // ---- GEMM1: relu(logX @ W1x + ZW1) ----
#pragma unroll
    for (int s = 0; s < 4; ++s) {
        short8 xv[4];
#pragma unroll
        for (int mt = 0; mt < 4; ++mt)
            xv[mt] = *(const short8*)&sH[wm * 64 + mt * 16 + ln][s * 32 + q * 8];
#pragma unroll
        for (int nt = 0; nt < 4; ++nt) {
            short8 wf = *(const short8*)(w1p + (size_t)(((((wn * 4 + nt) * 4) + s) << 6) + L) * 8);
#pragma unroll
            for (int mt = 0; mt < 4; ++mt)
                acc[mt][nt] = __builtin_amdgcn_mfma_f32_16x16x32_bf16(wf, xv[mt], acc[mt][nt], 0, 0, 0);
        }
    }
    __syncthreads();                                            // b2: Xp reads done
#pragma unroll
    for (int mt = 0; mt < 4; ++mt)
#pragma unroll
        for (int nt = 0; nt < 4; ++nt) {
            short4v pk;
            pk.x = bfb(fmaxf(acc[mt][nt][0], 0.f));
            pk.y = bfb(fmaxf(acc[mt][nt][1], 0.f));
            pk.z = bfb(fmaxf(acc[mt][nt][2], 0.f));
            pk.w = bfb(fmaxf(acc[mt][nt][3], 0.f));
            *(short4v*)&sH[wm * 64 + mt * 16 + ln][wn * 64 + nt * 16 + q * 4] = pk;
        }
    __syncthreads();                                            // b3: H0 ready

    // ---- GEMM2: H1 = relu(H0 @ W2 + b2), H1 stays in registers ----
#pragma unroll
    for (int nt = 0; nt < 4; ++nt) {
        float4 bv = *(const float4*)(b2 + wn * 64 + nt * 16 + q * 4);
        acc[0][nt] = (floatx4){bv.x, bv.y, bv.z, bv.w};
        acc[1][nt] = acc[0][nt];
        acc[2][nt] = acc[0][nt];
        acc[3][nt] = acc[0][nt];
    }
#pragma unroll
    for (int s = 0; s < 8; ++s) {
        short8 xv[4];
#pragma unroll
        for (int mt = 0; mt < 4; ++mt)
            xv[mt] = *(const short8*)&sH[wm * 64 + mt * 16 + ln][s * 32 + q * 8];
#pragma unroll
        for (int nt = 0; nt < 4; ++nt) {
            short8 wf = *(const short8*)(w2p + (size_t)(((((wn * 4 + nt) * 8) + s) << 6) + L) * 8);
#pragma unroll
            for (int mt = 0; mt < 4; ++mt)
                acc[mt][nt] = __builtin_amdgcn_mfma_f32_16x16x32_bf16(wf, xv[mt], acc[mt][nt], 0, 0, 0);
        }
    }

    // ---- GEMM3 (register-only): redistribute H1 frags in-wave, MFMA W3 ----
    // acc[mt][nt][r] = H1[n = wn*64+nt*16+q*4+r][cell = wm*64+mt*16+ln].
    // B-frag for k-step s=2wn+h needs lane (q,ln) to hold
    // H1[n = wn*64 + h*32 + q*8 + j][same cells]; source lane ((2q+(j>>2))&3,ln),
    // nt = 2h+(q>>1), r = j&3.
    int pk[4][4][2];
#pragma unroll
    for (int mt = 0; mt < 4; ++mt)
#pragma unroll
        for (int nt = 0; nt < 4; ++nt) {
            pk[mt][nt][0] = pack2(fmaxf(acc[mt][nt][0], 0.f), fmaxf(acc[mt][nt][1], 0.f));
            pk[mt][nt][1] = pack2(fmaxf(acc[mt][nt][2], 0.f), fmaxf(acc[mt][nt][3], 0.f));
        }
    const int lane0 = (((2 * q) & 3) << 4) + ln;
    const int lane1 = (((2 * q + 1) & 3) << 4) + ln;
    const bool hi = (q >> 1) != 0;
    floatx4 p3[4];
#pragma unroll
    for (int mt = 0; mt < 4; ++mt) p3[mt] = (floatx4){0.f, 0.f, 0.f, 0.f};
#pragma unroll
    for (int h = 0; h < 2; ++h) {
        short8 wf = *(const short8*)(w3p + (size_t)(((2 * wn + h) << 6) + L) * 8);
#pragma unroll
        for (int mt = 0; mt < 4; ++mt) {
            int a0 = __shfl(pk[mt][2 * h][0], lane0);
            int c0 = __shfl(pk[mt][2 * h + 1][0], lane0);
            int a1 = __shfl(pk[mt][2 * h][1], lane0);
            int c1 = __shfl(pk[mt][2 * h + 1][1], lane0);
            int a2 = __shfl(pk[mt][2 * h][0], lane1);
            int c2 = __shfl(pk[mt][2 * h + 1][0], lane1);
            int a3 = __shfl(pk[mt][2 * h][1], lane1);
            int c3 = __shfl(pk[mt][2 * h + 1][1], lane1);
            union { int i[4]; short8 s; } u;
            u.i[0] = hi ? c0 : a0;
            u.i[1] = hi ? c1 : a1;
            u.i[2] = hi ? c2 : a2;
            u.i[3] = hi ? c3 : a3;
            p3[mt] = __builtin_amdgcn_mfma_f32_16x16x32_bf16(wf, u.s, p3[mt], 0, 0, 0);
        }
    }
    __syncthreads();                                            // b4: H0 reads done
#pragma unroll
    for (int mt = 0; mt < 4; ++mt)
        *(floatx4*)&sP[wn][wm * 64 + mt * 16 + ln][q * 4] = p3[mt];
    __syncthreads();                                            // b5: sP ready

    // ---- combine 4 N-quarter partials + b3, staged coalesced atomics ----
    {
        int rep = blockIdx.x & (NREP - 1);
        float* accR = accs + (size_t)rep * (B_SAMP * D_OUT);
#pragma unroll
        for (int i = 0; i < 4; ++i) {
            int idx = tid + i * 512;      // 128 cells x 16 outs
            int m = idx >> 4, n = idx & 15;
            int cell = base + m;
            if (cell < N_CELLS) {
                float v = sP[0][m][n] + sP[1][m][n] + sP[2][m][n] + sP[3][m][n] + b3[n];
                atomicAdd(&accR[(size_t)sSI[m] * D_OUT + n], v);
            }
        }
    }
}

__global__ __launch_bounds__(256)
void finalize(const float* __restrict__ accs, const float* __restrict__ cnts,
              float* __restrict__ out) {
    int o = blockIdx.x * blockDim.x + threadIdx.x;   // 0..8191
    int s = o >> 4;
    float sum = 0.f, cnt = 0.f;
#pragma unroll 8
    for (int r = 0; r < NREP; ++r) {
        sum += accs[(size_t)r * (B_SAMP * D_OUT) + o];
        cnt += cnts[(size_t)r * B_SAMP + s];
    }
    out[o] = sum / fmaxf(cnt, 1.0f);
}

extern "C" void kernel_launch(void* const* d_in, const int* in_sizes, int n_in,
                              void* d_out, int out_size, void* d_ws, size_t ws_size,
                              hipStream_t stream) {
    const float* X   = (const float*)d_in[0];
    const float* Z   = (const float*)d_in[1];
    const float* W1  = (const float*)d_in[2];
    const float* b1  = (const float*)d_in[3];
    const float* W2  = (const float*)d_in[4];
    const float* b2  = (const float*)d_in[5];
    const float* W3  = (const float*)d_in[6];
    const float* b3  = (const float*)d_in[7];
    const int*   c2b = (const int*)d_in[8];
    const int*   sidx= (const int*)d_in[9];

    char* ws = (char*)d_ws;
    __hip_bfloat16* w1p = (__hip_bfloat16*)(ws + OFF_W1P);
    __hip_bfloat16* w2p = (__hip_bfloat16*)(ws + OFF_W2P);
    __hip_bfloat16* w3p = (__hip_bfloat16*)(ws + OFF_W3P);
    float* zw1  = (float*)(ws + OFF_ZW);
    float* accs = (float*)(ws + OFF_ACC);
    float* cnts = (float*)(ws + OFF_CNT);
    int*   c2s  = (int*)(ws + OFF_C2S);
    float* out  = (float*)d_out;

    // zero accs+cnts (contiguous); stream-ordered, graph-capture-safe
    hipMemsetAsync(accs, 0, (size_t)NREP * (B_SAMP * D_OUT + B_SAMP) * 4, stream);

    prep<<<W1_BLKS + W2_BLKS + W3_BLKS + ZW_BLKS + C2S_BLKS, 256, 0, stream>>>(
        W1, b1, W2, W3, Z, c2b, sidx, w1p, w2p, w3p, zw1, cnts, c2s);

    fused_mlp<<<NBLK, 512, 0, stream>>>(X, c2b, c2s, b2, b3,
                                        w1p, w2p, w3p, zw1, accs, cnts);
    finalize<<<32, 256, 0, stream>>>(accs, cnts, out);
}

// Round 6
// 508.770 us; speedup vs baseline: 1.0459x; 1.0459x over previous
//
#include <hip/hip_runtime.h>
#include <hip/hip_bf16.h>

typedef __attribute__((ext_vector_type(8))) short short8;
typedef __attribute__((ext_vector_type(4))) short short4v;
typedef __attribute__((ext_vector_type(4))) float floatx4;

#define N_CELLS  500000
#define B_SAMP   512
#define D_X      128
#define D_Z      32
#define H_DIM    256
#define D_OUT    16

#define M_TILE   64
#define NBLK     7813          // ceil(500000/64); last block has 32 valid cells
#define LDA      136           // Xp LDS row stride (bf16)
#define LDH      264           // H LDS row stride (bf16)
#define SP_LD    20            // GEMM3 partial row stride (f32)

#define NREP     64

// workspace layout (bytes), 16B aligned
#define OFF_W1P   0            // 16*4*512*2   = 65536
#define OFF_W2P   65536        // 16*8*512*2   = 131072
#define OFF_W3P   196608       // 1*8*512*2    = 8192
#define OFF_ZW    204800       // 512*256*4    = 524288
#define OFF_ACC   729088       // 64*8192*4    = 2097152
#define OFF_CNT   2826240      // 64*512*4     = 131072
#define OFF_C2S   2957312      // 500000*4     = 2000000

#define W1_BLKS   128
#define W2_BLKS   256
#define W3_BLKS   16
#define ZW_BLKS   512
#define C2S_BLKS  1954

__device__ __forceinline__ short bfb(float x) {
    union { __hip_bfloat16 h; short s; } u;
    u.h = __float2bfloat16(x);
    return u.s;
}

// prep: pack W1(K=128, ln2-folded)/W2/W3 into MFMA fragment order;
// ZW1[b][n] = Z[b,:]@W1[128:160,n] + b1[n]; c2s[cell]=sidx[c2b[cell]];
// counts histogram (MLP-independent) into replicated cnts.
// accs/cnts zeroed by hipMemsetAsync before this launch.
__global__ __launch_bounds__(256)
void prep(const float* __restrict__ W1, const float* __restrict__ b1,
          const float* __restrict__ W2, const float* __restrict__ W3,
          const float* __restrict__ Z,
          const int* __restrict__ c2b, const int* __restrict__ sidx,
          __hip_bfloat16* __restrict__ w1p, __hip_bfloat16* __restrict__ w2p,
          __hip_bfloat16* __restrict__ w3p, float* __restrict__ zw1,
          float* __restrict__ cnts, int* __restrict__ c2s) {
    int bid = blockIdx.x;
    int tid = threadIdx.x;
    if (bid < W1_BLKS + W2_BLKS + W3_BLKS) {
        const float* W; __hip_bfloat16* dst; int N, kS, idx; float scale;
        if (bid < W1_BLKS) {
            idx = bid * 256 + tid; W = W1; dst = w1p; N = H_DIM; kS = 4;
            scale = 0.6931471805599453f;          // ln2: staging uses log2
        } else if (bid < W1_BLKS + W2_BLKS) {
            idx = (bid - W1_BLKS) * 256 + tid; W = W2; dst = w2p; N = H_DIM; kS = 8;
            scale = 1.0f;
        } else {
            idx = (bid - W1_BLKS - W2_BLKS) * 256 + tid; W = W3; dst = w3p; N = D_OUT; kS = 8;
            scale = 1.0f;
        }
        int j = idx & 7;
        int L = (idx >> 3) & 63;
        int s = (idx >> 9) % kS;
        int t = idx / (kS << 9);
        int k = s * 32 + ((L >> 4) << 3) + j;
        int n = t * 16 + (L & 15);
        dst[idx] = __float2bfloat16(W[(size_t)k * N + n] * scale);
        return;
    }
    bid -= W1_BLKS + W2_BLKS + W3_BLKS;
    if (bid < ZW_BLKS) {
        int s = bid;
        float a = b1[tid];
        const float* zr = Z + (size_t)s * D_Z;
        const float* wr = W1 + (size_t)D_X * H_DIM + tid;
#pragma unroll 8
        for (int k = 0; k < D_Z; ++k) a += zr[k] * wr[(size_t)k * H_DIM];
        zw1[(size_t)s * H_DIM + tid] = a;
        return;
    }
    bid -= ZW_BLKS;
    int i = bid * 256 + tid;
    if (i < N_CELLS) {
        int si = sidx[c2b[i]];
        c2s[i] = si;
        atomicAdd(&cnts[(size_t)(bid & (NREP - 1)) * B_SAMP + si], 1.0f);
    }
}

// 64 cells/block, 512 threads (8 waves: 2 cell-halves x 4 N-quarters).
// r3 structure + explicit weight-fragment software pipeline (2-deep): step
// s+1's W-frags load from L2 while step s's MFMAs run; GEMM2 step-0 frags
// issued before the H0 barrier (drain completes them); GEMM3 frags preloaded
// during GEMM2's last step; ZW gathers + W1-step0 + b3 issued at entry under
// X staging. launch_bounds(512,4) for register headroom.
__global__ __launch_bounds__(512, 4)
void fused_mlp(const float* __restrict__ X, const int* __restrict__ c2b,
               const int* __restrict__ c2s, const float* __restrict__ b2,
               const float* __restrict__ b3,
               const __hip_bfloat16* __restrict__ w1p,
               const __hip_bfloat16* __restrict__ w2p,
               const __hip_bfloat16* __restrict__ w3p,
               const float* __restrict__ zw1,
               float* __restrict__ accs, float* __restrict__ cnts) {
    __shared__ __align__(16) short sX[M_TILE * LDA];   // Xp; aliased as GEMM3 partials
    __shared__ short sH[M_TILE][LDH];                  // H0 then H1 (in-place)
    __shared__ int sSI[M_TILE];
    short (*xp)[LDA] = (short (*)[LDA])sX;
    float (*sP)[M_TILE][SP_LD] = (float (*)[M_TILE][SP_LD])sX;  // [2][64][20]

    const int tid = threadIdx.x;
    const int w   = tid >> 6;     // wave 0..7
    const int L   = tid & 63;
    const int q   = L >> 4;
    const int ln  = L & 15;
    const int wm  = w >> 2;       // cell-half
    const int wn  = w & 3;        // N-quarter
    const int base = blockIdx.x * M_TILE;

    // ---- entry prefetches: W1 step-0 frags, ZW gathers (acc init), b3 ----
    short8 wfc[4], wfn[4];
#pragma unroll
    for (int nt = 0; nt < 4; ++nt)
        wfc[nt] = *(const short8*)(w1p + (size_t)((((wn * 4 + nt) * 4) << 6) + L) * 8);

    int g0 = base + wm * 32 + ln;      if (g0 >= N_CELLS) g0 = N_CELLS - 1;
    int g1 = base + wm * 32 + 16 + ln; if (g1 >= N_CELLS) g1 = N_CELLS - 1;
    int cb0 = c2b[g0];
    int cb1 = c2b[g1];
    floatx4 acc[2][4];
#pragma unroll
    for (int nt = 0; nt < 4; ++nt) {
        acc[0][nt] = *(const floatx4*)(zw1 + (size_t)cb0 * H_DIM + wn * 64 + nt * 16 + q * 4);
        acc[1][nt] = *(const floatx4*)(zw1 + (size_t)cb1 * H_DIM + wn * 64 + nt * 16 + q * 4);
    }
    float b3v = b3[tid & 15];

    // ---- stage Xp = log2(1+X) bf16 (K=128; Z folded into ZW1) ----
#pragma unroll
    for (int i = 0; i < 4; ++i) {
        int idx = tid + i * 512;          // 64 rows * 32 float4
        int row = idx >> 5, c4 = idx & 31;
        int gr = base + row; if (gr >= N_CELLS) gr = N_CELLS - 1;
        float4 v = *(const float4*)(X + (size_t)gr * D_X + c4 * 4);
        short4v pk;
        pk.x = bfb(__log2f(1.0f + v.x));
        pk.y = bfb(__log2f(1.0f + v.y));
        pk.z = bfb(__log2f(1.0f + v.z));
        pk.w = bfb(__log2f(1.0f + v.w));
        *(short4v*)&xp[row][c4 * 4] = pk;
    }
    if (tid < M_TILE) {
        int gr = base + tid; if (gr >= N_CELLS) gr = N_CELLS - 1;
        sSI[tid] = c2s[gr];
    }
    __syncthreads();                                            // B1: Xp ready

    // ---- GEMM1: relu(logX @ W1x + ZW1), 2-deep wf pipeline ----
#pragma unroll
    for (int s = 0; s < 4; ++s) {
        if (s < 3) {
#pragma unroll
            for (int nt = 0; nt < 4; ++nt)
                wfn[nt] = *(const short8*)(w1p + (size_t)(((((wn * 4 + nt) * 4) + s + 1) << 6) + L) * 8);
        }
        short8 x0 = *(const short8*)&xp[wm * 32 + ln][s * 32 + q * 8];
        short8 x1 = *(const short8*)&xp[wm * 32 + 16 + ln][s * 32 + q * 8];
#pragma unroll
        for (int nt = 0; nt < 4; ++nt) {
            acc[0][nt] = __builtin_amdgcn_mfma_f32_16x16x32_bf16(wfc[nt], x0, acc[0][nt], 0, 0, 0);
            acc[1][nt] = __builtin_amdgcn_mfma_f32_16x16x32_bf16(wfc[nt], x1, acc[1][nt], 0, 0, 0);
        }
        if (s < 3) {
#pragma unroll
            for (int nt = 0; nt < 4; ++nt) wfc[nt] = wfn[nt];
        }
    }
    // issue GEMM2 step-0 frags now; B2's drain completes them for free
#pragma unroll
    for (int nt = 0; nt < 4; ++nt)
        wfc[nt] = *(const short8*)(w2p + (size_t)((((wn * 4 + nt) * 8) << 6) + L) * 8);
    float4 bv[4];
#pragma unroll
    for (int nt = 0; nt < 4; ++nt)
        bv[nt] = *(const float4*)(b2 + wn * 64 + nt * 16 + q * 4);
    // H0 epilogue
#pragma unroll
    for (int nt = 0; nt < 4; ++nt) {
        short4v p0, p1;
        p0.x = bfb(fmaxf(acc[0][nt][0], 0.f));
        p0.y = bfb(fmaxf(acc[0][nt][1], 0.f));
        p0.z = bfb(fmaxf(acc[0][nt][2], 0.f));
        p0.w = bfb(fmaxf(acc[0][nt][3], 0.f));
        p1.x = bfb(fmaxf(acc[1][nt][0], 0.f));
        p1.y = bfb(fmaxf(acc[1][nt][1], 0.f));
        p1.z = bfb(fmaxf(acc[1][nt][2], 0.f));
        p1.w = bfb(fmaxf(acc[1][nt][3], 0.f));
        *(short4v*)&sH[wm * 32 + ln][wn * 64 + nt * 16 + q * 4] = p0;
        *(short4v*)&sH[wm * 32 + 16 + ln][wn * 64 + nt * 16 + q * 4] = p1;
    }
    __syncthreads();                                            // B2: H0 ready

    // ---- GEMM2: relu(H0 @ W2 + b2), 2-deep wf pipeline; last step preloads W3 ----
    const int kh = w >> 2;   // GEMM3 K-half
#pragma unroll
    for (int nt = 0; nt < 4; ++nt) {
        acc[0][nt] = (floatx4){bv[nt].x, bv[nt].y, bv[nt].z, bv[nt].w};
        acc[1][nt] = acc[0][nt];
    }
#pragma unroll
    for (int s = 0; s < 8; ++s) {
        if (s < 7) {
#pragma unroll
            for (int nt = 0; nt < 4; ++nt)
                wfn[nt] = *(const short8*)(w2p + (size_t)(((((wn * 4 + nt) * 8) + s + 1) << 6) + L) * 8);
        } else {
            // preload GEMM3 frags for this wave's K-half
#pragma unroll
            for (int ss = 0; ss < 4; ++ss)
                wfn[ss] = *(const short8*)(w3p + (size_t)(((kh * 4 + ss) << 6) + L) * 8);
        }
        short8 x0 = *(const short8*)&sH[wm * 32 + ln][s * 32 + q * 8];
        short8 x1 = *(const short8*)&sH[wm * 32 + 16 + ln][s * 32 + q * 8];
#pragma unroll
        for (int nt = 0; nt < 4; ++nt) {
            acc[0][nt] = __builtin_amdgcn_mfma_f32_16x16x32_bf16(wfc[nt], x0, acc[0][nt], 0, 0, 0);
            acc[1][nt] = __builtin_amdgcn_mfma_f32_16x16x32_bf16(wfc[nt], x1, acc[1][nt], 0, 0, 0);
        }
#pragma unroll
        for (int nt = 0; nt < 4; ++nt) wfc[nt] = wfn[nt];
    }
    __syncthreads();                                            // B3: H0 reads done
    // H1 epilogue (in-place)
#pragma unroll
    for (int nt = 0; nt < 4; ++nt) {
        short4v p0, p1;
        p0.x = bfb(fmaxf(acc[0][nt][0], 0.f));
        p0.y = bfb(fmaxf(acc[0][nt][1], 0.f));
        p0.z = bfb(fmaxf(acc[0][nt][2], 0.f));
        p0.w = bfb(fmaxf(acc[0][nt][3], 0.f));
        p1.x = bfb(fmaxf(acc[1][nt][0], 0.f));
        p1.y = bfb(fmaxf(acc[1][nt][1], 0.f));
        p1.z = bfb(fmaxf(acc[1][nt][2], 0.f));
        p1.w = bfb(fmaxf(acc[1][nt][3], 0.f));
        *(short4v*)&sH[wm * 32 + ln][wn * 64 + nt * 16 + q * 4] = p0;
        *(short4v*)&sH[wm * 32 + 16 + ln][wn * 64 + nt * 16 + q * 4] = p1;
    }
    __syncthreads();                                            // B4: H1 ready

    // ---- GEMM3: 8 waves = 4 cell-groups x 2 K-halves; frags already in wfc ----
    {
        int g = w & 3;
        floatx4 a3 = (floatx4){0.f, 0.f, 0.f, 0.f};
#pragma unroll
        for (int ss = 0; ss < 4; ++ss) {
            int s = kh * 4 + ss;
            short8 hv = *(const short8*)&sH[g * 16 + ln][s * 32 + q * 8];
            a3 = __builtin_amdgcn_mfma_f32_16x16x32_bf16(wfc[ss], hv, a3, 0, 0, 0);
        }
        *(floatx4*)&sP[kh][g * 16 + ln][q * 4] = a3;   // sX alias: reads done pre-B2
    }
    __syncthreads();                                            // B5: sP ready

    // ---- combine K-halves + b3, staged coalesced atomics ----
    {
        int rep = blockIdx.x & (NREP - 1);
        float* accR = accs + (size_t)rep * (B_SAMP * D_OUT);
#pragma unroll
        for (int i = 0; i < 2; ++i) {
            int idx = tid + i * 512;      // 64 cells x 16 outs
            int m = idx >> 4, n = idx & 15;
            int cell = base + m;
            if (cell < N_CELLS) {
                float v = sP[0][m][n] + sP[1][m][n] + b3v;
                atomicAdd(&accR[(size_t)sSI[m] * D_OUT + n], v);
            }
        }
    }
}

__global__ __launch_bounds__(256)
void finalize(const float* __restrict__ accs, const float* __restrict__ cnts,
              float* __restrict__ out) {
    int o = blockIdx.x * blockDim.x + threadIdx.x;   // 0..8191
    int s = o >> 4;
    float sum = 0.f, cnt = 0.f;
#pragma unroll 8
    for (int r = 0; r < NREP; ++r) {
        sum += accs[(size_t)r * (B_SAMP * D_OUT) + o];
        cnt += cnts[(size_t)r * B_SAMP + s];
    }
    out[o] = sum / fmaxf(cnt, 1.0f);
}

extern "C" void kernel_launch(void* const* d_in, const int* in_sizes, int n_in,
                              void* d_out, int out_size, void* d_ws, size_t ws_size,
                              hipStream_t stream) {
    const float* X   = (const float*)d_in[0];
    const float* Z   = (const float*)d_in[1];
    const float* W1  = (const float*)d_in[2];
    const float* b1  = (const float*)d_in[3];
    const float* W2  = (const float*)d_in[4];
    const float* b2  = (const float*)d_in[5];
    const float* W3  = (const float*)d_in[6];
    const float* b3  = (const float*)d_in[7];
    const int*   c2b = (const int*)d_in[8];
    const int*   sidx= (const int*)d_in[9];

    char* ws = (char*)d_ws;
    __hip_bfloat16* w1p = (__hip_bfloat16*)(ws + OFF_W1P);
    __hip_bfloat16* w2p = (__hip_bfloat16*)(ws + OFF_W2P);
    __hip_bfloat16* w3p = (__hip_bfloat16*)(ws + OFF_W3P);
    float* zw1  = (float*)(ws + OFF_ZW);
    float* accs = (float*)(ws + OFF_ACC);
    float* cnts = (float*)(ws + OFF_CNT);
    int*   c2s  = (int*)(ws + OFF_C2S);
    float* out  = (float*)d_out;

    // zero accs+cnts (contiguous); stream-ordered, graph-capture-safe
    hipMemsetAsync(accs, 0, (size_t)NREP * (B_SAMP * D_OUT + B_SAMP) * 4, stream);

    prep<<<W1_BLKS + W2_BLKS + W3_BLKS + ZW_BLKS + C2S_BLKS, 256, 0, stream>>>(
        W1, b1, W2, W3, Z, c2b, sidx, w1p, w2p, w3p, zw1, cnts, c2s);

    fused_mlp<<<NBLK, 512, 0, stream>>>(X, c2b, c2s, b2, b3,
                                        w1p, w2p, w3p, zw1, accs, cnts);
    finalize<<<32, 256, 0, stream>>>(accs, cnts, out);
}

// Round 7
// 467.663 us; speedup vs baseline: 1.1379x; 1.0879x over previous
//
#include <hip/hip_runtime.h>
#include <hip/hip_bf16.h>

typedef __attribute__((ext_vector_type(8))) short short8;
typedef __attribute__((ext_vector_type(4))) short short4v;
typedef __attribute__((ext_vector_type(4))) float floatx4;

#define N_CELLS  500000
#define B_SAMP   512
#define D_X      128
#define D_Z      32
#define H_DIM    256
#define D_OUT    16

#define M_TILE   64
#define NBLK     7813          // ceil(500000/64); last block has 32 valid cells
#define LDA      128           // xp row stride (shorts), pow2 + XOR swizzle
#define LDH      256           // sH row stride (shorts), pow2 + XOR swizzle
#define SP_LD    20            // GEMM3 partial row stride (f32)

// XOR swizzle: flips 16B-block bits of the short-index by row&7.
// All writes are >=4-short aligned, reads 8-short aligned -> alignment-safe.
#define SWZ(c, r) ((c) ^ (((r) & 7) << 3))

#define NREP     64

// workspace layout (bytes), 16B aligned
#define OFF_W1P   0            // 16*4*512*2   = 65536
#define OFF_W2P   65536        // 16*8*512*2   = 131072
#define OFF_W3P   196608       // 1*8*512*2    = 8192
#define OFF_ZW    204800       // 512*256*4    = 524288
#define OFF_ACC   729088       // 64*8192*4    = 2097152
#define OFF_CNT   2826240      // 64*512*4     = 131072
#define OFF_C2S   2957312      // 500000*4     = 2000000

#define W1_BLKS   128
#define W2_BLKS   256
#define W3_BLKS   16
#define ZW_BLKS   512
#define C2S_BLKS  1954

__device__ __forceinline__ short bfb(float x) {
    union { __hip_bfloat16 h; short s; } u;
    u.h = __float2bfloat16(x);
    return u.s;
}

// prep: pack W1(K=128, ln2-folded)/W2/W3 into MFMA fragment order;
// ZW1[b][n] = Z[b,:]@W1[128:160,n] + b1[n]; c2s[cell]=sidx[c2b[cell]];
// counts histogram (MLP-independent) into replicated cnts.
// accs/cnts zeroed by hipMemsetAsync before this launch.
__global__ __launch_bounds__(256)
void prep(const float* __restrict__ W1, const float* __restrict__ b1,
          const float* __restrict__ W2, const float* __restrict__ W3,
          const float* __restrict__ Z,
          const int* __restrict__ c2b, const int* __restrict__ sidx,
          __hip_bfloat16* __restrict__ w1p, __hip_bfloat16* __restrict__ w2p,
          __hip_bfloat16* __restrict__ w3p, float* __restrict__ zw1,
          float* __restrict__ cnts, int* __restrict__ c2s) {
    int bid = blockIdx.x;
    int tid = threadIdx.x;
    if (bid < W1_BLKS + W2_BLKS + W3_BLKS) {
        const float* W; __hip_bfloat16* dst; int N, kS, idx; float scale;
        if (bid < W1_BLKS) {
            idx = bid * 256 + tid; W = W1; dst = w1p; N = H_DIM; kS = 4;
            scale = 0.6931471805599453f;          // ln2: staging uses log2
        } else if (bid < W1_BLKS + W2_BLKS) {
            idx = (bid - W1_BLKS) * 256 + tid; W = W2; dst = w2p; N = H_DIM; kS = 8;
            scale = 1.0f;
        } else {
            idx = (bid - W1_BLKS - W2_BLKS) * 256 + tid; W = W3; dst = w3p; N = D_OUT; kS = 8;
            scale = 1.0f;
        }
        int j = idx & 7;
        int L = (idx >> 3) & 63;
        int s = (idx >> 9) % kS;
        int t = idx / (kS << 9);
        int k = s * 32 + ((L >> 4) << 3) + j;
        int n = t * 16 + (L & 15);
        dst[idx] = __float2bfloat16(W[(size_t)k * N + n] * scale);
        return;
    }
    bid -= W1_BLKS + W2_BLKS + W3_BLKS;
    if (bid < ZW_BLKS) {
        int s = bid;
        float a = b1[tid];
        const float* zr = Z + (size_t)s * D_Z;
        const float* wr = W1 + (size_t)D_X * H_DIM + tid;
#pragma unroll 8
        for (int k = 0; k < D_Z; ++k) a += zr[k] * wr[(size_t)k * H_DIM];
        zw1[(size_t)s * H_DIM + tid] = a;
        return;
    }
    bid -= ZW_BLKS;
    int i = bid * 256 + tid;
    if (i < N_CELLS) {
        int si = sidx[c2b[i]];
        c2s[i] = si;
        atomicAdd(&cnts[(size_t)(bid & (NREP - 1)) * B_SAMP + si], 1.0f);
    }
}

// 64 cells/block, 512 threads, 8 waves: N-EIGHTH layout — each wave owns 32
// N-columns over ALL 64 cells (acc[4 m-frags][2 n-frags]). Every weight
// fragment is loaded from L2 exactly once per tile (was twice). All LDS
// tiles use pow2 row strides + XOR swizzle (col ^ (row&7)<<3) -> conflict-
// free ds_read_b128/b64. 5 barriers/tile; GEMM2 in-place; sP aliases xp.
__global__ __launch_bounds__(512, 4)
void fused_mlp(const float* __restrict__ X, const int* __restrict__ c2b,
               const int* __restrict__ c2s, const float* __restrict__ b2,
               const float* __restrict__ b3,
               const __hip_bfloat16* __restrict__ w1p,
               const __hip_bfloat16* __restrict__ w2p,
               const __hip_bfloat16* __restrict__ w3p,
               const float* __restrict__ zw1,
               float* __restrict__ accs, float* __restrict__ cnts) {
    __shared__ __align__(16) short sX[M_TILE * LDA];   // xp; aliased as sP later
    __shared__ __align__(16) short sH[M_TILE][LDH];    // H0 then H1 (in-place)
    __shared__ int sSI[M_TILE];
    short (*xp)[LDA] = (short (*)[LDA])sX;
    float (*sP)[M_TILE][SP_LD] = (float (*)[M_TILE][SP_LD])sX;  // [2][64][20]

    const int tid = threadIdx.x;
    const int w   = tid >> 6;     // wave 0..7 = N-eighth owner
    const int L   = tid & 63;
    const int q   = L >> 4;
    const int ln  = L & 15;
    const int wn  = w;            // 32 n-columns: [wn*32, wn*32+32)
    const int base = blockIdx.x * M_TILE;

    // ---- GEMM1 C-init: gather ZW1 rows (bias + Z-part precomputed) ----
    floatx4 acc[4][2];
#pragma unroll
    for (int mt = 0; mt < 4; ++mt) {
        int g = base + mt * 16 + ln; if (g >= N_CELLS) g = N_CELLS - 1;
        int cbm = c2b[g];
#pragma unroll
        for (int nt = 0; nt < 2; ++nt)
            acc[mt][nt] = *(const floatx4*)(zw1 + (size_t)cbm * H_DIM + wn * 32 + nt * 16 + q * 4);
    }
    float b3v = b3[tid & 15];

    // ---- stage Xp = log2(1+X) bf16 into xp (swizzled) ----
#pragma unroll
    for (int i = 0; i < 4; ++i) {
        int idx = tid + i * 512;          // 64 rows * 32 float4
        int row = idx >> 5, c4 = idx & 31;
        int gr = base + row; if (gr >= N_CELLS) gr = N_CELLS - 1;
        float4 v = *(const float4*)(X + (size_t)gr * D_X + c4 * 4);
        short4v pk;
        pk.x = bfb(__log2f(1.0f + v.x));
        pk.y = bfb(__log2f(1.0f + v.y));
        pk.z = bfb(__log2f(1.0f + v.z));
        pk.w = bfb(__log2f(1.0f + v.w));
        *(short4v*)&xp[row][SWZ(c4 * 4, row)] = pk;
    }
    if (tid < M_TILE) {
        int gr = base + tid; if (gr >= N_CELLS) gr = N_CELLS - 1;
        sSI[tid] = c2s[gr];
    }
    __syncthreads();                                            // B1: Xp ready

    // ---- GEMM1: relu(logX @ W1x + ZW1) -> sH (each wf loaded once/tile) ----
#pragma unroll
    for (int s = 0; s < 4; ++s) {
        short8 xv[4];
#pragma unroll
        for (int mt = 0; mt < 4; ++mt)
            xv[mt] = *(const short8*)&xp[mt * 16 + ln][SWZ(s * 32 + q * 8, ln)];
#pragma unroll
        for (int nt = 0; nt < 2; ++nt) {
            int t = wn * 2 + nt;
            short8 wf = *(const short8*)(w1p + (size_t)(((t * 4 + s) << 6) + L) * 8);
#pragma unroll
            for (int mt = 0; mt < 4; ++mt)
                acc[mt][nt] = __builtin_amdgcn_mfma_f32_16x16x32_bf16(wf, xv[mt], acc[mt][nt], 0, 0, 0);
        }
    }
#pragma unroll
    for (int mt = 0; mt < 4; ++mt)
#pragma unroll
        for (int nt = 0; nt < 2; ++nt) {
            short4v pk;
            pk.x = bfb(fmaxf(acc[mt][nt][0], 0.f));
            pk.y = bfb(fmaxf(acc[mt][nt][1], 0.f));
            pk.z = bfb(fmaxf(acc[mt][nt][2], 0.f));
            pk.w = bfb(fmaxf(acc[mt][nt][3], 0.f));
            *(short4v*)&sH[mt * 16 + ln][SWZ(wn * 32 + nt * 16 + q * 4, ln)] = pk;
        }
    __syncthreads();                                            // B2: H0 ready

    // ---- GEMM2: relu(H0 @ W2 + b2), in-place on sH ----
#pragma unroll
    for (int nt = 0; nt < 2; ++nt) {
        float4 bv = *(const float4*)(b2 + wn * 32 + nt * 16 + q * 4);
        floatx4 b = (floatx4){bv.x, bv.y, bv.z, bv.w};
#pragma unroll
        for (int mt = 0; mt < 4; ++mt) acc[mt][nt] = b;
    }
#pragma unroll
    for (int s = 0; s < 8; ++s) {
        short8 xv[4];
#pragma unroll
        for (int mt = 0; mt < 4; ++mt)
            xv[mt] = *(const short8*)&sH[mt * 16 + ln][SWZ(s * 32 + q * 8, ln)];
#pragma unroll
        for (int nt = 0; nt < 2; ++nt) {
            int t = wn * 2 + nt;
            short8 wf = *(const short8*)(w2p + (size_t)(((t * 8 + s) << 6) + L) * 8);
#pragma unroll
            for (int mt = 0; mt < 4; ++mt)
                acc[mt][nt] = __builtin_amdgcn_mfma_f32_16x16x32_bf16(wf, xv[mt], acc[mt][nt], 0, 0, 0);
        }
    }
    __syncthreads();                                            // B3: H0 reads done
#pragma unroll
    for (int mt = 0; mt < 4; ++mt)
#pragma unroll
        for (int nt = 0; nt < 2; ++nt) {
            short4v pk;
            pk.x = bfb(fmaxf(acc[mt][nt][0], 0.f));
            pk.y = bfb(fmaxf(acc[mt][nt][1], 0.f));
            pk.z = bfb(fmaxf(acc[mt][nt][2], 0.f));
            pk.w = bfb(fmaxf(acc[mt][nt][3], 0.f));
            *(short4v*)&sH[mt * 16 + ln][SWZ(wn * 32 + nt * 16 + q * 4, ln)] = pk;
        }
    __syncthreads();                                            // B4: H1 ready

    // ---- GEMM3: 8 waves = 4 cell-groups x 2 K-halves -> sP (xp alias) ----
    {
        int g  = w & 3;
        int kh = w >> 2;
        floatx4 a3 = (floatx4){0.f, 0.f, 0.f, 0.f};
#pragma unroll
        for (int ss = 0; ss < 4; ++ss) {
            int s = kh * 4 + ss;
            short8 hv = *(const short8*)&sH[g * 16 + ln][SWZ(s * 32 + q * 8, ln)];
            short8 wf = *(const short8*)(w3p + (size_t)((s << 6) + L) * 8);
            a3 = __builtin_amdgcn_mfma_f32_16x16x32_bf16(wf, hv, a3, 0, 0, 0);
        }
        *(floatx4*)&sP[kh][g * 16 + ln][q * 4] = a3;   // xp reads ended pre-B2
    }
    __syncthreads();                                            // B5: sP ready

    // ---- combine K-halves + b3, staged coalesced atomics ----
    {
        int rep = blockIdx.x & (NREP - 1);
        float* accR = accs + (size_t)rep * (B_SAMP * D_OUT);
#pragma unroll
        for (int i = 0; i < 2; ++i) {
            int idx = tid + i * 512;      // 64 cells x 16 outs
            int m = idx >> 4, n = idx & 15;
            int cell = base + m;
            if (cell < N_CELLS) {
                float v = sP[0][m][n] + sP[1][m][n] + b3v;
                atomicAdd(&accR[(size_t)sSI[m] * D_OUT + n], v);
            }
        }
    }
}

__global__ __launch_bounds__(256)
void finalize(const float* __restrict__ accs, const float* __restrict__ cnts,
              float* __restrict__ out) {
    int o = blockIdx.x * blockDim.x + threadIdx.x;   // 0..8191
    int s = o >> 4;
    float sum = 0.f, cnt = 0.f;
#pragma unroll 8
    for (int r = 0; r < NREP; ++r) {
        sum += accs[(size_t)r * (B_SAMP * D_OUT) + o];
        cnt += cnts[(size_t)r * B_SAMP + s];
    }
    out[o] = sum / fmaxf(cnt, 1.0f);
}

extern "C" void kernel_launch(void* const* d_in, const int* in_sizes, int n_in,
                              void* d_out, int out_size, void* d_ws, size_t ws_size,
                              hipStream_t stream) {
    const float* X   = (const float*)d_in[0];
    const float* Z   = (const float*)d_in[1];
    const float* W1  = (const float*)d_in[2];
    const float* b1  = (const float*)d_in[3];
    const float* W2  = (const float*)d_in[4];
    const float* b2  = (const float*)d_in[5];
    const float* W3  = (const float*)d_in[6];
    const float* b3  = (const float*)d_in[7];
    const int*   c2b = (const int*)d_in[8];
    const int*   sidx= (const int*)d_in[9];

    char* ws = (char*)d_ws;
    __hip_bfloat16* w1p = (__hip_bfloat16*)(ws + OFF_W1P);
    __hip_bfloat16* w2p = (__hip_bfloat16*)(ws + OFF_W2P);
    __hip_bfloat16* w3p = (__hip_bfloat16*)(ws + OFF_W3P);
    float* zw1  = (float*)(ws + OFF_ZW);
    float* accs = (float*)(ws + OFF_ACC);
    float* cnts = (float*)(ws + OFF_CNT);
    int*   c2s  = (int*)(ws + OFF_C2S);
    float* out  = (float*)d_out;

    // zero accs+cnts (contiguous); stream-ordered, graph-capture-safe
    hipMemsetAsync(accs, 0, (size_t)NREP * (B_SAMP * D_OUT + B_SAMP) * 4, stream);

    prep<<<W1_BLKS + W2_BLKS + W3_BLKS + ZW_BLKS + C2S_BLKS, 256, 0, stream>>>(
        W1, b1, W2, W3, Z, c2b, sidx, w1p, w2p, w3p, zw1, cnts, c2s);

    fused_mlp<<<NBLK, 512, 0, stream>>>(X, c2b, c2s, b2, b3,
                                        w1p, w2p, w3p, zw1, accs, cnts);
    finalize<<<32, 256, 0, stream>>>(accs, cnts, out);
}